// Round 4
// baseline (3963.036 us; speedup 1.0000x reference)
//
#include <hip/hip_runtime.h>
#include <hip/hip_bf16.h>

// Problem constants: inputs [T,B,D], state [B,H], W_xh [D,H], W_hh [H,H], b_h [H]
#define T_STEPS 256
#define B_SZ    64
#define D_SZ    1024
#define H_SZ    2048
#define NBLK    256     // persistent blocks, 1/CU (coop-launched)
#define TPB     320     // waves 0-3 = compute (K-split), wave 4 = clock-burn
#define HBUF    (B_SZ * H_SZ)   // one h buffer: 131072 fp16 = 256 KB

// fp16 everywhere (2^-11 rounding). Weights stored x256 so all entries are
// fp16-normal (W ~ U(0,0.01)); accumulator scaled by 1/256 in epilogue.
#define W_SCALE     256.0f
#define W_INV_SCALE 0.00390625f

// Sentinel: fp16 NaN 0x7FFF. tanh outputs lie in [-1,1] -> never NaN, so a
// ull == SENT means "not yet written" (each ull is written by ONE atomic 8B
// store -> no tearing; any non-sentinel ull is fully valid).
#define SENT_ULL 0x7FFF7FFF7FFF7FFFull

typedef __attribute__((ext_vector_type(8))) _Float16 f16x8;  // 8 fp16 (4 VGPRs)
typedef __attribute__((ext_vector_type(4))) _Float16 f16x4;
typedef __attribute__((ext_vector_type(4))) float    f32x4;  // MFMA 16x16 accumulator

// ---------------- fused prep kernel ----------------
// One launch: cvt inputs, 2 transposes, cvt state, ctr zero, sentinel fill.
#define PREP_NI   16384                       // inputs cvt: n_in/4 / 256
#define PREP_NTX  (64 * 32)                   // W_xh transpose tiles (H/32 x D/32)
#define PREP_NTH  (64 * 64)                   // W_hh transpose tiles
#define PREP_NS   128                         // state cvt: B*H/4 / 256
#define PREP_NC   1                           // ctr zero
#define PREP_NF   16384                       // sentinel fill: 64MB / (256*16B)
#define PREP_TOT  (PREP_NI + PREP_NTX + PREP_NTH + PREP_NS + PREP_NC + PREP_NF)

__device__ __forceinline__ void tile_transpose(
    const float* __restrict__ in, _Float16* __restrict__ out,
    int rows, int cols, int bx, int by, float scale, float (*tile)[33]) {
    int tx = threadIdx.x & 31, ty = threadIdx.x >> 5;   // 32x8 threads
    int r0 = by * 32, c0 = bx * 32;
#pragma unroll
    for (int i = 0; i < 32; i += 8)
        tile[ty + i][tx] = in[(size_t)(r0 + ty + i) * cols + c0 + tx];
    __syncthreads();
#pragma unroll
    for (int i = 0; i < 32; i += 8)
        out[(size_t)(c0 + ty + i) * rows + r0 + tx] = (_Float16)(tile[tx][ty + i] * scale);
}

__global__ void prep_all(const float* __restrict__ inputs, _Float16* __restrict__ xin,
                         const float* __restrict__ W_xh, _Float16* __restrict__ WxT,
                         const float* __restrict__ W_hh, _Float16* __restrict__ WhT,
                         const float* __restrict__ state, _Float16* __restrict__ h0,
                         unsigned int* __restrict__ ctr, uint4* __restrict__ sfill) {
    __shared__ float tile[32][33];
    int bid = blockIdx.x, tid = threadIdx.x;
    if (bid < PREP_NI) {
        int i = bid * 256 + tid;
        float4 v = ((const float4*)inputs)[i];
        f16x4 o = { (_Float16)v.x, (_Float16)v.y, (_Float16)v.z, (_Float16)v.w };
        ((f16x4*)xin)[i] = o;
    } else if (bid < PREP_NI + PREP_NTX) {
        int rel = bid - PREP_NI;
        tile_transpose(W_xh, WxT, D_SZ, H_SZ, rel % 64, rel / 64, W_SCALE, tile);
    } else if (bid < PREP_NI + PREP_NTX + PREP_NTH) {
        int rel = bid - PREP_NI - PREP_NTX;
        tile_transpose(W_hh, WhT, H_SZ, H_SZ, rel % 64, rel / 64, W_SCALE, tile);
    } else if (bid < PREP_NI + PREP_NTX + PREP_NTH + PREP_NS) {
        int rel = bid - PREP_NI - PREP_NTX - PREP_NTH;
        int i = rel * 256 + tid;
        float4 v = ((const float4*)state)[i];
        f16x4 o = { (_Float16)v.x, (_Float16)v.y, (_Float16)v.z, (_Float16)v.w };
        ((f16x4*)h0)[i] = o;
    } else if (bid < PREP_NI + PREP_NTX + PREP_NTH + PREP_NS + PREP_NC) {
#pragma unroll
        for (int k = 0; k < 4; k++) ctr[k * 256 + tid] = 0u;
    } else if (sfill) {
        int rel = bid - (PREP_NI + PREP_NTX + PREP_NTH + PREP_NS + PREP_NC);
        uint4 s = { 0x7FFF7FFFu, 0x7FFF7FFFu, 0x7FFF7FFFu, 0x7FFF7FFFu };
        sfill[(size_t)rel * 256 + tid] = s;
    }
}

// ---------------- phase 1: x_proj = inputs @ W_xh + b_h ----------------
// R12 (proven): m97-structure GEMM — 128x128 tile, BK=32, global_load_lds
// width-16 staging (linear LDS dest), 2-barrier K-loop, 4x4 acc/wave.
#define GBK 32
__device__ __forceinline__ void gload_lds16(const _Float16* g, _Float16* l) {
    __builtin_amdgcn_global_load_lds((const __attribute__((address_space(1))) void*)g,
                                     (__attribute__((address_space(3))) void*)l, 16, 0, 0);
}

__global__ __launch_bounds__(256) void gemm_xproj(
    const _Float16* __restrict__ A,      // [M,K] fp16
    const _Float16* __restrict__ BT,     // [N,K] fp16 (W^T, x256)
    const float* __restrict__ bias,
    float* __restrict__ C,               // [M,N] fp32
    int M, int N, int K)
{
    __shared__ _Float16 As[128 * GBK];   // 8 KB, row-major [128][32]
    __shared__ _Float16 Bs[128 * GBK];   // 8 KB

    int tid  = threadIdx.x;
    int wave = tid >> 6;
    int lane = tid & 63;
    int q = lane >> 4;
    int r = lane & 15;
    int m0 = blockIdx.x * 128;
    int n0 = blockIdx.y * 128;
    int wr = (wave >> 1) * 64;           // wave's 64x64 sub-tile
    int wc = (wave & 1) * 64;

    int srow  = lane >> 2;
    int skoff = (lane & 3) * 8;

    f32x4 acc[4][4] = {};
    for (int k0 = 0; k0 < K; k0 += GBK) {
#pragma unroll
        for (int i = 0; i < 2; i++) {
            int chunk = wave * 2 + i;
            int row = chunk * 16 + srow;
            gload_lds16(A  + (size_t)(m0 + row) * K + k0 + skoff, As + chunk * 512);
            gload_lds16(BT + (size_t)(n0 + row) * K + k0 + skoff, Bs + chunk * 512);
        }
        __asm__ volatile("s_waitcnt vmcnt(0)" ::: "memory");
        __syncthreads();

        f16x8 a[4], b[4];
#pragma unroll
        for (int i = 0; i < 4; i++)
            a[i] = *(const f16x8*)(As + (wr + i * 16 + r) * GBK + q * 8);
#pragma unroll
        for (int j = 0; j < 4; j++)
            b[j] = *(const f16x8*)(Bs + (wc + j * 16 + r) * GBK + q * 8);
#pragma unroll
        for (int i = 0; i < 4; i++)
#pragma unroll
            for (int j = 0; j < 4; j++)
                acc[i][j] = __builtin_amdgcn_mfma_f32_16x16x32_f16(a[i], b[j], acc[i][j], 0, 0, 0);
        __syncthreads();
    }
#pragma unroll
    for (int i = 0; i < 4; i++)
#pragma unroll
        for (int j = 0; j < 4; j++)
#pragma unroll
            for (int reg = 0; reg < 4; reg++) {
                int row = m0 + wr + i * 16 + q * 4 + reg;   // C/D: col=lane&15, row=(lane>>4)*4+reg
                int col = n0 + wc + j * 16 + r;
                C[(size_t)row * N + col] = acc[i][j][reg] * W_INV_SCALE + bias[col];
            }
}

// ---------------- phase 2: persistent recurrence ----------------
// R14 (CHAIN): SENTINEL-DATA sync — no flags, no barrier, no acks.
// Chain slots 1..256 are pre-filled with fp16-NaN (0x7FFF) by prep. A ull of
// h is written by ONE atomic 8B agent store, so ull != SENT <=> fully valid
// (tanh in [-1,1] can never be 0x7FFF). Consumers poll their OWN h addresses
// with agent ull loads (L1/L2-bypass -> no stale-line deadlock; fresh chain
// addresses every step) until no sentinel, with s_sleep backoff.
// Critical chain shrinks from {store-ack, hdone1, 32-way contended atomic
// add, parity poll RT, go fanout, h-load RT} to {store one-way, poll
// observe} — and the consumer's poll load overlaps its own store drain.
// R13 lesson respected: pollers/line ~64 (each h line needed by exactly one
// wave per block), spread over ~512 lines/group — no MALL line hotspot.
// WAR on part[] closed by LDS pread flags. Drift bounded by data deps
// (systolic). Burn wave kept; go only signals exit now.
// Fallback (!CHAIN, ping-pong buffers): R10 barrier version verbatim.
template<bool CHAIN>
__global__ __launch_bounds__(TPB, 1) void rnn_persist(
    _Float16* __restrict__ hbase,          // CHAIN: h_0 of chain; else ping buf
    _Float16* __restrict__ hb1,            // pong buf (fallback only)
    const _Float16* __restrict__ WT,       // [H,H] fp16 = W_hh^T x256
    float* __restrict__ out,               // [T,B,H] fp32: x_proj in, h out (in place)
    float* __restrict__ final_out,         // [B,H] fp32
    unsigned int* __restrict__ ctr)        // barrier region (fallback only, pre-zeroed)
{
    __shared__ f16x8 wfrag[8192];                   // [kb][half][lane] = 128 KB
    __shared__ float part[4][2][256];               // [w][half][lane*4+reg] = 8 KB
    __shared__ __align__(16) _Float16 hsl[16 * 32]; // 1 KB block h tile
    __shared__ int pdone[4];                        // per-wave partial flags
    __shared__ int pread[2];                        // part-consumed flags (CHAIN WAR)
    __shared__ int hdone1, go;                      // monotonic flags

    int tid = threadIdx.x;
    int bid = blockIdx.x;
    int g   = (bid >> 1) & 3;                    // row group (XCD-pair under round-robin)
    int c   = ((bid >> 3) << 1) | (bid & 1);     // col range 0..63
    int n0  = c * 32;
    int row0 = g * 16;                           // block's 16 batch rows

    if (tid == 0) {
        pdone[0] = pdone[1] = pdone[2] = pdone[3] = 0;
        pread[0] = pread[1] = 0;
        hdone1 = 0; go = 0;
    }

    // one-time W staging into fragment order: idx = (kb*2+half)*64 + l
    for (int idx = tid; idx < 8192; idx += TPB) {
        int kb = idx >> 7, j = (idx >> 6) & 1, l = idx & 63;
        wfrag[idx] = *(const f16x8*)(WT + (size_t)(n0 + j * 16 + (l & 15)) * H_SZ
                                        + kb * 32 + (l >> 4) * 8);
    }
    __syncthreads();   // the ONLY block-wide barrier (covers flag init)

    int wave = tid >> 6, lane = tid & 63;

    if (wave == 4) {
        // dedicated clock keep-alive: 4 independent FMA chains, poll LDS exit flag
        float c0 = 1.0f + lane, c1 = 2.0f, c2 = 3.0f, c3 = 4.0f;
        const float k1 = 1.0000001f, k2 = 1.0e-30f;
        while (__hip_atomic_load(&go, __ATOMIC_RELAXED, __HIP_MEMORY_SCOPE_WORKGROUP) < T_STEPS) {
#pragma unroll
            for (int z = 0; z < 64; z++) {
                c0 = __builtin_fmaf(c0, k1, k2);
                c1 = __builtin_fmaf(c1, k1, k2);
                c2 = __builtin_fmaf(c2, k1, k2);
                c3 = __builtin_fmaf(c3, k1, k2);
            }
        }
        __asm__ volatile("" :: "v"(c0), "v"(c1), "v"(c2), "v"(c3));
        return;
    }

    int q = lane >> 4, r = lane & 15;
    unsigned int* aline = ctr + (g * 2 + (bid & 1)) * 32;   // fallback parity line

    // reducer-layout x_proj prefetch for t=0 (waves 0,1 only):
    // elem s -> row = (lane>>4)+4s, col = lane&15, column half = wave
    float xp[4];
    if (wave < 2) {
#pragma unroll
        for (int s = 0; s < 4; s++)
            xp[s] = out[(size_t)(row0 + q + 4 * s) * H_SZ + n0 + wave * 16 + r];
    }

    union AU { unsigned long long u[2]; f16x8 v; };

    for (int t = 0; t < T_STEPS; t++) {
        const _Float16* hp;
        _Float16*       hn;
        if constexpr (CHAIN) {
            hp = hbase + (size_t)t * HBUF;
            hn = hbase + (size_t)(t + 1) * HBUF;
        } else {
            hp = (t & 1) ? hb1 : hbase;
            hn = (t & 1) ? hbase : hb1;
        }
        float* out_t = out + (size_t)t * B_SZ * H_SZ;
        int tg = t + 1;

        // ---- A stream: this wave's K-slice (16 rows x 512 cols) ----
        const _Float16* arow = hp + (size_t)(row0 + r) * H_SZ + q * 8;
        AU ab[16];
        if constexpr (CHAIN) {
            // sentinel poll: re-issue all 32 agent ull loads until no NaN word
            const unsigned long long* abase = (const unsigned long long*)arow;
            for (;;) {
#pragma unroll
                for (int p = 0; p < 16; p++) {
                    const unsigned long long* a = abase + (size_t)(wave * 16 + p) * 8;
                    ab[p].u[0] = __hip_atomic_load(a,     __ATOMIC_RELAXED, __HIP_MEMORY_SCOPE_AGENT);
                    ab[p].u[1] = __hip_atomic_load(a + 1, __ATOMIC_RELAXED, __HIP_MEMORY_SCOPE_AGENT);
                }
                bool bad = false;
#pragma unroll
                for (int p = 0; p < 16; p++)
                    bad = bad | (ab[p].u[0] == SENT_ULL) | (ab[p].u[1] == SENT_ULL);
                if (__ballot(bad) == 0ull) break;
                __builtin_amdgcn_s_sleep(2);
            }
            __asm__ volatile("" ::: "memory");
        } else {
#pragma unroll
            for (int p = 0; p < 16; p++) {
                ab[p].u[0] = __hip_atomic_load((unsigned long long*)(arow + (wave * 16 + p) * 32),
                                               __ATOMIC_RELAXED, __HIP_MEMORY_SCOPE_AGENT);
                ab[p].u[1] = __hip_atomic_load((unsigned long long*)(arow + (wave * 16 + p) * 32) + 1,
                                               __ATOMIC_RELAXED, __HIP_MEMORY_SCOPE_AGENT);
            }
        }

        f32x4 acc[2] = {};
#pragma unroll
        for (int p = 0; p < 16; p++) {
            int kb = wave * 16 + p;
            acc[0] = __builtin_amdgcn_mfma_f32_16x16x32_f16(ab[p].v, wfrag[kb * 128 + lane],      acc[0], 0, 0, 0);
            acc[1] = __builtin_amdgcn_mfma_f32_16x16x32_f16(ab[p].v, wfrag[kb * 128 + 64 + lane], acc[1], 0, 0, 0);
        }

        // CHAIN WAR guard: step t-1's part[] must be consumed before overwrite
        if constexpr (CHAIN) {
            if (t > 0) {
                while (__hip_atomic_load(&pread[0], __ATOMIC_RELAXED, __HIP_MEMORY_SCOPE_WORKGROUP) < t ||
                       __hip_atomic_load(&pread[1], __ATOMIC_RELAXED, __HIP_MEMORY_SCOPE_WORKGROUP) < t) { }
                __asm__ volatile("" ::: "memory");
            }
        }

        // partials to LDS (b128, conflict-free), then flag
#pragma unroll
        for (int h = 0; h < 2; h++)
            *(f32x4*)&part[wave][h][lane * 4] = acc[h];
        __asm__ volatile("s_waitcnt lgkmcnt(0)" ::: "memory");
        if (lane == 0)
            __hip_atomic_store(&pdone[wave], tg, __ATOMIC_RELAXED, __HIP_MEMORY_SCOPE_WORKGROUP);

        if (wave >= 2) {
            if (t == T_STEPS - 1) break;
            if constexpr (!CHAIN) {
                while (__hip_atomic_load(&go, __ATOMIC_RELAXED, __HIP_MEMORY_SCOPE_WORKGROUP) < tg) { }
            }
            continue;   // CHAIN: next step's sentinel poll gates progress
        }

        // ---- reducer path (wave 0 = col half 0, wave 1 = col half 1) ----
        for (int w = 0; w < 4; w++)
            if (w != wave)
                while (__hip_atomic_load(&pdone[w], __ATOMIC_RELAXED, __HIP_MEMORY_SCOPE_WORKGROUP) < tg) { }
        __asm__ volatile("" ::: "memory");

        bool last = (t == T_STEPS - 1);

        if constexpr (CHAIN) {
            float sums[4];
#pragma unroll
            for (int s = 0; s < 4; s++) {
                int idx = (s * 16 + r) * 4 + q;   // producer layout: ((row>>2)*16+col)*4+(row&3)
                sums[s] = part[0][wave][idx] + part[1][wave][idx]
                        + part[2][wave][idx] + part[3][wave][idx];
            }
            if (lane == 0)
                __hip_atomic_store(&pread[wave], tg, __ATOMIC_RELAXED, __HIP_MEMORY_SCOPE_WORKGROUP);

            float vv[4];
#pragma unroll
            for (int s = 0; s < 4; s++) {
                vv[s] = tanhf(sums[s] * W_INV_SCALE + xp[s]);
                hsl[(q + 4 * s) * 32 + wave * 16 + r] = (_Float16)vv[s];
            }
            // h store FIRST (critical path for all consumers), fire-and-forget
            if (!last) {
                __asm__ volatile("s_waitcnt lgkmcnt(0)" ::: "memory");
                int rl = lane >> 2, pi = wave * 4 + (lane & 3);
                unsigned long long hv = ((const unsigned long long*)hsl)[rl * 8 + pi];
                __hip_atomic_store((unsigned long long*)(hn + (size_t)(row0 + rl) * H_SZ + n0) + pi,
                                   hv, __ATOMIC_RELAXED, __HIP_MEMORY_SCOPE_AGENT);
            }
            // non-critical outputs
#pragma unroll
            for (int s = 0; s < 4; s++) {
                size_t o = (size_t)(row0 + q + 4 * s) * H_SZ + n0 + wave * 16 + r;
                out_t[o] = vv[s];
                if (last) final_out[o] = vv[s];
            }
            if (last) {
                if (wave == 0 && lane == 0)
                    __hip_atomic_store(&go, T_STEPS, __ATOMIC_RELAXED, __HIP_MEMORY_SCOPE_WORKGROUP);
                break;
            }
            // prefetch next step's x_proj (h-independent)
            const float* out_t1 = out_t + B_SZ * H_SZ;
#pragma unroll
            for (int s = 0; s < 4; s++)
                xp[s] = out_t1[(size_t)(row0 + q + 4 * s) * H_SZ + n0 + wave * 16 + r];
            continue;   // no barrier: consumers self-pace on sentinels
        } else {
            // ---- fallback: R10 barrier tail (proven) ----
#pragma unroll
            for (int s = 0; s < 4; s++) {
                int row = q + 4 * s;
                int idx = (s * 16 + r) * 4 + q;
                float sum = part[0][wave][idx] + part[1][wave][idx]
                          + part[2][wave][idx] + part[3][wave][idx];
                float v = tanhf(sum * W_INV_SCALE + xp[s]);
                size_t o = (size_t)(row0 + row) * H_SZ + n0 + wave * 16 + r;
                out_t[o] = v;
                if (last) final_out[o] = v;
                hsl[row * 32 + wave * 16 + r] = (_Float16)v;
            }
            if (last) {
                if (wave == 0 && lane == 0)
                    __hip_atomic_store(&go, T_STEPS, __ATOMIC_RELAXED, __HIP_MEMORY_SCOPE_WORKGROUP);
                break;
            }
            const float* out_t1 = out_t + B_SZ * H_SZ;
#pragma unroll
            for (int s = 0; s < 4; s++)
                xp[s] = out_t1[(size_t)(row0 + q + 4 * s) * H_SZ + n0 + wave * 16 + r];

            __asm__ volatile("s_waitcnt lgkmcnt(0)" ::: "memory");
            {
                int rl = lane >> 2, pi = wave * 4 + (lane & 3);
                unsigned long long vv = ((const unsigned long long*)hsl)[rl * 8 + pi];
                __hip_atomic_store((unsigned long long*)(hn + (size_t)(row0 + rl) * H_SZ + n0) + pi,
                                   vv, __ATOMIC_RELAXED, __HIP_MEMORY_SCOPE_AGENT);
            }
            __builtin_amdgcn_s_waitcnt(0);   // h stores acked at coherence point

            if (wave == 1) {
                if (lane == 0)
                    __hip_atomic_store(&hdone1, tg, __ATOMIC_RELAXED, __HIP_MEMORY_SCOPE_WORKGROUP);
                while (__hip_atomic_load(&go, __ATOMIC_RELAXED, __HIP_MEMORY_SCOPE_WORKGROUP) < tg) { }
                continue;
            }
            while (__hip_atomic_load(&hdone1, __ATOMIC_RELAXED, __HIP_MEMORY_SCOPE_WORKGROUP) < tg) { }
            if (lane == 0)
                __hip_atomic_fetch_add(aline, 1u, __ATOMIC_RELAXED, __HIP_MEMORY_SCOPE_AGENT);
            unsigned int line_tgt = (unsigned int)tg * 32u;
            for (;;) {
                unsigned int v = __hip_atomic_load(ctr + (g * 2 + (lane & 1)) * 32,
                                                   __ATOMIC_RELAXED, __HIP_MEMORY_SCOPE_AGENT);
                if (__ballot(v < line_tgt) == 0ull) break;
            }
            if (lane == 0)
                __hip_atomic_store(&go, tg, __ATOMIC_RELAXED, __HIP_MEMORY_SCOPE_WORKGROUP);
        }
    }
}

// ---------------- launcher ----------------

extern "C" void kernel_launch(void* const* d_in, const int* in_sizes, int n_in,
                              void* d_out, int out_size, void* d_ws, size_t ws_size,
                              hipStream_t stream) {
    const float* inputs = (const float*)d_in[0];   // [T,B,D]
    const float* state  = (const float*)d_in[1];   // [B,H]
    const float* W_xh   = (const float*)d_in[2];   // [D,H]
    const float* W_hh   = (const float*)d_in[3];   // [H,H]
    const float* b_h    = (const float*)d_in[4];   // [H]
    float* out = (float*)d_out;
    char* ws = (char*)d_ws;

    const size_t MB = 1ull << 20;
    const size_t XIN_BYTES = (size_t)T_STEPS * B_SZ * D_SZ * 2;   // 32 MB fp16 inputs

    // chain layout: [WxT 4MB][WhT 8MB][ctr 8KB][xin 32MB][h chain: 257 x 256KB]
    // xin must NOT alias the chain: chain slots 1..256 get sentinel-prefilled.
    // (ws >= ~108.5 MB verified available: R1's identically-sized layout ran.)
    const size_t OFF_WXT   = 0;
    const size_t OFF_WHT   = 4 * MB;
    const size_t OFF_CTR   = 12 * MB;
    const size_t OFF_XIN   = 12 * MB + 8192;
    const size_t OFF_CHAIN = OFF_XIN + XIN_BYTES;
    const size_t NEED_CHAIN = OFF_CHAIN + (size_t)(T_STEPS + 1) * HBUF * 2;

    // fallback (ping-pong) layout
    const size_t F_IN  = 0;
    const size_t F_WXT = F_IN  + XIN_BYTES;
    const size_t F_WHT = F_WXT + (size_t)H_SZ * D_SZ * 2;
    const size_t F_H0  = F_WHT + (size_t)H_SZ * H_SZ * 2;
    const size_t F_H1  = F_H0  + (size_t)HBUF * 2;
    const size_t F_CTR = F_H1  + (size_t)HBUF * 2;
    const size_t NEED_PP = F_CTR + 4096;

    dim3 g1((T_STEPS * B_SZ) / 128, H_SZ / 128);
    float* final_out = out + (size_t)T_STEPS * B_SZ * H_SZ;

    if (ws_size >= NEED_CHAIN) {
        _Float16* WxT    = (_Float16*)(ws + OFF_WXT);
        _Float16* WhT    = (_Float16*)(ws + OFF_WHT);
        unsigned int* ctr = (unsigned int*)(ws + OFF_CTR);
        _Float16* xin    = (_Float16*)(ws + OFF_XIN);
        _Float16* hchain = (_Float16*)(ws + OFF_CHAIN);          // h_0
        _Float16* hb1 = nullptr;

        prep_all<<<PREP_TOT, 256, 0, stream>>>(inputs, xin, W_xh, WxT,
                                               W_hh, WhT, state, hchain, ctr,
                                               (uint4*)(hchain + HBUF));

        gemm_xproj<<<g1, 256, 0, stream>>>(xin, WxT, b_h, out,
                                           T_STEPS * B_SZ, H_SZ, D_SZ);

        void* args[] = { (void*)&hchain, (void*)&hb1, (void*)&WhT,
                         (void*)&out, (void*)&final_out, (void*)&ctr };
        hipLaunchCooperativeKernel((void*)rnn_persist<true>, dim3(NBLK), dim3(TPB),
                                   args, 0, stream);
    } else {
        if (ws_size < NEED_PP) return;
        _Float16* inputs_f16 = (_Float16*)(ws + F_IN);
        _Float16* WxT    = (_Float16*)(ws + F_WXT);
        _Float16* WhT    = (_Float16*)(ws + F_WHT);
        _Float16* hbuf0  = (_Float16*)(ws + F_H0);
        _Float16* hbuf1  = (_Float16*)(ws + F_H1);
        unsigned int* ctr = (unsigned int*)(ws + F_CTR);

        prep_all<<<PREP_TOT, 256, 0, stream>>>(inputs, inputs_f16, W_xh, WxT,
                                               W_hh, WhT, state, hbuf0, ctr,
                                               (uint4*)nullptr);

        gemm_xproj<<<g1, 256, 0, stream>>>(inputs_f16, WxT, b_h, out,
                                           T_STEPS * B_SZ, H_SZ, D_SZ);

        void* args[] = { (void*)&hbuf0, (void*)&hbuf1, (void*)&WhT,
                         (void*)&out, (void*)&final_out, (void*)&ctr };
        hipLaunchCooperativeKernel((void*)rnn_persist<false>, dim3(NBLK), dim3(TPB),
                                   args, 0, stream);
    }
}

// Round 5
// 1500.324 us; speedup vs baseline: 2.6415x; 2.6415x over previous
//
#include <hip/hip_runtime.h>
#include <hip/hip_bf16.h>

// Problem constants: inputs [T,B,D], state [B,H], W_xh [D,H], W_hh [H,H], b_h [H]
#define T_STEPS 256
#define B_SZ    64
#define D_SZ    1024
#define H_SZ    2048
#define NBLK    256     // persistent blocks, 1/CU (coop-launched)
#define TPB     320     // waves 0-3 = compute (K-split), wave 4 = clock-burn
#define HBUF    (B_SZ * H_SZ)   // one h buffer: 131072 fp16 = 256 KB

// fp16 everywhere (2^-11 rounding). Weights stored x256 so all entries are
// fp16-normal (W ~ U(0,0.01)); accumulator scaled by 1/256 in epilogue.
#define W_SCALE     256.0f
#define W_INV_SCALE 0.00390625f

// Sentinel: fp16 NaN 0x7FFF. tanh outputs lie in [-1,1] -> never 0x7FFF. Each
// 8B h unit is written by ONE atomic store -> a ull is either SENT or valid.
#define SENT_ULL 0x7FFF7FFF7FFF7FFFull

typedef __attribute__((ext_vector_type(8))) _Float16 f16x8;  // 8 fp16 (4 VGPRs)
typedef __attribute__((ext_vector_type(4))) _Float16 f16x4;
typedef __attribute__((ext_vector_type(4))) float    f32x4;  // MFMA 16x16 accumulator

// ---------------- fused prep kernel ----------------
// One launch: cvt inputs, 2 transposes, cvt state, ctr zero, sentinel fill.
#define PREP_NI   16384                       // inputs cvt: n_in/4 / 256
#define PREP_NTX  (64 * 32)                   // W_xh transpose tiles (H/32 x D/32)
#define PREP_NTH  (64 * 64)                   // W_hh transpose tiles
#define PREP_NS   128                         // state cvt: B*H/4 / 256
#define PREP_NC   1                           // ctr zero
#define PREP_NF   16384                       // sentinel fill: 64MB / (256*16B)
#define PREP_TOT  (PREP_NI + PREP_NTX + PREP_NTH + PREP_NS + PREP_NC + PREP_NF)

__device__ __forceinline__ void tile_transpose(
    const float* __restrict__ in, _Float16* __restrict__ out,
    int rows, int cols, int bx, int by, float scale, float (*tile)[33]) {
    int tx = threadIdx.x & 31, ty = threadIdx.x >> 5;   // 32x8 threads
    int r0 = by * 32, c0 = bx * 32;
#pragma unroll
    for (int i = 0; i < 32; i += 8)
        tile[ty + i][tx] = in[(size_t)(r0 + ty + i) * cols + c0 + tx];
    __syncthreads();
#pragma unroll
    for (int i = 0; i < 32; i += 8)
        out[(size_t)(c0 + ty + i) * rows + r0 + tx] = (_Float16)(tile[tx][ty + i] * scale);
}

__global__ void prep_all(const float* __restrict__ inputs, _Float16* __restrict__ xin,
                         const float* __restrict__ W_xh, _Float16* __restrict__ WxT,
                         const float* __restrict__ W_hh, _Float16* __restrict__ WhT,
                         const float* __restrict__ state, _Float16* __restrict__ h0,
                         unsigned int* __restrict__ ctr, uint4* __restrict__ sfill) {
    __shared__ float tile[32][33];
    int bid = blockIdx.x, tid = threadIdx.x;
    if (bid < PREP_NI) {
        int i = bid * 256 + tid;
        float4 v = ((const float4*)inputs)[i];
        f16x4 o = { (_Float16)v.x, (_Float16)v.y, (_Float16)v.z, (_Float16)v.w };
        ((f16x4*)xin)[i] = o;
    } else if (bid < PREP_NI + PREP_NTX) {
        int rel = bid - PREP_NI;
        tile_transpose(W_xh, WxT, D_SZ, H_SZ, rel % 64, rel / 64, W_SCALE, tile);
    } else if (bid < PREP_NI + PREP_NTX + PREP_NTH) {
        int rel = bid - PREP_NI - PREP_NTX;
        tile_transpose(W_hh, WhT, H_SZ, H_SZ, rel % 64, rel / 64, W_SCALE, tile);
    } else if (bid < PREP_NI + PREP_NTX + PREP_NTH + PREP_NS) {
        int rel = bid - PREP_NI - PREP_NTX - PREP_NTH;
        int i = rel * 256 + tid;
        float4 v = ((const float4*)state)[i];
        f16x4 o = { (_Float16)v.x, (_Float16)v.y, (_Float16)v.z, (_Float16)v.w };
        ((f16x4*)h0)[i] = o;
    } else if (bid < PREP_NI + PREP_NTX + PREP_NTH + PREP_NS + PREP_NC) {
#pragma unroll
        for (int k = 0; k < 4; k++) ctr[k * 256 + tid] = 0u;
    } else if (sfill) {
        int rel = bid - (PREP_NI + PREP_NTX + PREP_NTH + PREP_NS + PREP_NC);
        uint4 s = { 0x7FFF7FFFu, 0x7FFF7FFFu, 0x7FFF7FFFu, 0x7FFF7FFFu };
        sfill[(size_t)rel * 256 + tid] = s;
    }
}

// ---------------- phase 1: x_proj = inputs @ W_xh + b_h ----------------
// R12 (proven): m97-structure GEMM — 128x128 tile, BK=32, global_load_lds
// width-16 staging (linear LDS dest), 2-barrier K-loop, 4x4 acc/wave.
#define GBK 32
__device__ __forceinline__ void gload_lds16(const _Float16* g, _Float16* l) {
    __builtin_amdgcn_global_load_lds((const __attribute__((address_space(1))) void*)g,
                                     (__attribute__((address_space(3))) void*)l, 16, 0, 0);
}

__global__ __launch_bounds__(256) void gemm_xproj(
    const _Float16* __restrict__ A,      // [M,K] fp16
    const _Float16* __restrict__ BT,     // [N,K] fp16 (W^T, x256)
    const float* __restrict__ bias,
    float* __restrict__ C,               // [M,N] fp32
    int M, int N, int K)
{
    __shared__ _Float16 As[128 * GBK];   // 8 KB, row-major [128][32]
    __shared__ _Float16 Bs[128 * GBK];   // 8 KB

    int tid  = threadIdx.x;
    int wave = tid >> 6;
    int lane = tid & 63;
    int q = lane >> 4;
    int r = lane & 15;
    int m0 = blockIdx.x * 128;
    int n0 = blockIdx.y * 128;
    int wr = (wave >> 1) * 64;           // wave's 64x64 sub-tile
    int wc = (wave & 1) * 64;

    int srow  = lane >> 2;
    int skoff = (lane & 3) * 8;

    f32x4 acc[4][4] = {};
    for (int k0 = 0; k0 < K; k0 += GBK) {
#pragma unroll
        for (int i = 0; i < 2; i++) {
            int chunk = wave * 2 + i;
            int row = chunk * 16 + srow;
            gload_lds16(A  + (size_t)(m0 + row) * K + k0 + skoff, As + chunk * 512);
            gload_lds16(BT + (size_t)(n0 + row) * K + k0 + skoff, Bs + chunk * 512);
        }
        __asm__ volatile("s_waitcnt vmcnt(0)" ::: "memory");
        __syncthreads();

        f16x8 a[4], b[4];
#pragma unroll
        for (int i = 0; i < 4; i++)
            a[i] = *(const f16x8*)(As + (wr + i * 16 + r) * GBK + q * 8);
#pragma unroll
        for (int j = 0; j < 4; j++)
            b[j] = *(const f16x8*)(Bs + (wc + j * 16 + r) * GBK + q * 8);
#pragma unroll
        for (int i = 0; i < 4; i++)
#pragma unroll
            for (int j = 0; j < 4; j++)
                acc[i][j] = __builtin_amdgcn_mfma_f32_16x16x32_f16(a[i], b[j], acc[i][j], 0, 0, 0);
        __syncthreads();
    }
#pragma unroll
    for (int i = 0; i < 4; i++)
#pragma unroll
        for (int j = 0; j < 4; j++)
#pragma unroll
            for (int reg = 0; reg < 4; reg++) {
                int row = m0 + wr + i * 16 + q * 4 + reg;   // C/D: col=lane&15, row=(lane>>4)*4+reg
                int col = n0 + wc + j * 16 + r;
                C[(size_t)row * N + col] = acc[i][j][reg] * W_INV_SCALE + bias[col];
            }
}

// ---------------- phase 2: persistent recurrence ----------------
// R15 = R10 structure + ACK-FREE producer tail.
// R10 (proven 5.35us/step): K split across 4 compute waves; plain cached h
// loads on FRESH chain addresses (compulsory L2 miss -> one MALL fetch,
// L2-served for same-XCD blocks; R14 proved atomic/bypass loads are 2.8x
// worse); LDS partial reduce by waves 0/1; flat parity-line barrier.
// R15 change: producer no longer drains stores (s_waitcnt(0) ~900cy MALL
// ack REMOVED from critical chain). Barrier arrive is issued right after
// store ISSUE. Correctness: chain slots 1..256 are sentinel-prefilled
// (fp16 NaN); consumers do the SAME plain loads as R10 plus one register
// sentinel check; in the rare race-lost case they re-read their 16
// fragments with L2-bypassing atomic loads until valid (bounded, self-
// healing even if a stale sentinel line got cached). Fast path = R10
// exactly, zero extra MALL ops, zero extra pollers (R13 lesson).
// Waves>=2 go-wait restored -> reducers consumed part[] before go rises
// (no pread flags needed). Burn wave = wave 4.
template<bool CHAIN>
__global__ __launch_bounds__(TPB, 1) void rnn_persist(
    _Float16* __restrict__ hbase,          // CHAIN: h_0 of chain; else ping buf
    _Float16* __restrict__ hb1,            // pong buf (fallback only)
    const _Float16* __restrict__ WT,       // [H,H] fp16 = W_hh^T x256
    float* __restrict__ out,               // [T,B,H] fp32: x_proj in, h out (in place)
    float* __restrict__ final_out,         // [B,H] fp32
    unsigned int* __restrict__ ctr)        // barrier region (pre-zeroed)
{
    __shared__ f16x8 wfrag[8192];                   // [kb][half][lane] = 128 KB
    __shared__ float part[4][2][256];               // [w][half][lane*4+reg] = 8 KB
    __shared__ __align__(16) _Float16 hsl[16 * 32]; // 1 KB block h tile
    __shared__ int pdone[4];                        // per-wave partial flags
    __shared__ int hdone1, go;                      // monotonic flags

    int tid = threadIdx.x;
    int bid = blockIdx.x;
    int g   = (bid >> 1) & 3;                    // row group (XCD-pair under round-robin)
    int c   = ((bid >> 3) << 1) | (bid & 1);     // col range 0..63
    int n0  = c * 32;
    int row0 = g * 16;                           // block's 16 batch rows

    if (tid == 0) {
        pdone[0] = pdone[1] = pdone[2] = pdone[3] = 0;
        hdone1 = 0; go = 0;
    }

    // one-time W staging into fragment order: idx = (kb*2+half)*64 + l
    for (int idx = tid; idx < 8192; idx += TPB) {
        int kb = idx >> 7, j = (idx >> 6) & 1, l = idx & 63;
        wfrag[idx] = *(const f16x8*)(WT + (size_t)(n0 + j * 16 + (l & 15)) * H_SZ
                                        + kb * 32 + (l >> 4) * 8);
    }
    __syncthreads();   // the ONLY block-wide barrier (covers flag init)

    int wave = tid >> 6, lane = tid & 63;

    if (wave == 4) {
        // dedicated clock keep-alive: 4 independent FMA chains, poll LDS exit flag
        float c0 = 1.0f + lane, c1 = 2.0f, c2 = 3.0f, c3 = 4.0f;
        const float k1 = 1.0000001f, k2 = 1.0e-30f;
        while (__hip_atomic_load(&go, __ATOMIC_RELAXED, __HIP_MEMORY_SCOPE_WORKGROUP) < T_STEPS) {
#pragma unroll
            for (int z = 0; z < 64; z++) {
                c0 = __builtin_fmaf(c0, k1, k2);
                c1 = __builtin_fmaf(c1, k1, k2);
                c2 = __builtin_fmaf(c2, k1, k2);
                c3 = __builtin_fmaf(c3, k1, k2);
            }
        }
        __asm__ volatile("" :: "v"(c0), "v"(c1), "v"(c2), "v"(c3));
        return;
    }

    int q = lane >> 4, r = lane & 15;
    unsigned int* aline = ctr + (g * 2 + (bid & 1)) * 32;   // group parity arrival line

    // reducer-layout x_proj prefetch for t=0 (waves 0,1 only):
    // elem s -> row = (lane>>4)+4s, col = lane&15, column half = wave
    float xp[4];
    if (wave < 2) {
#pragma unroll
        for (int s = 0; s < 4; s++)
            xp[s] = out[(size_t)(row0 + q + 4 * s) * H_SZ + n0 + wave * 16 + r];
    }

    union AU { unsigned long long u[2]; f16x8 v; };

    for (int t = 0; t < T_STEPS; t++) {
        const _Float16* hp;
        _Float16*       hn;
        if constexpr (CHAIN) {
            hp = hbase + (size_t)t * HBUF;
            hn = hbase + (size_t)(t + 1) * HBUF;
        } else {
            hp = (t & 1) ? hb1 : hbase;
            hn = (t & 1) ? hbase : hb1;
        }
        float* out_t = out + (size_t)t * B_SZ * H_SZ;
        int tg = t + 1;

        // ---- A stream: this wave's K-slice, plain cached loads (R10 path) ----
        const _Float16* arow = hp + (size_t)(row0 + r) * H_SZ + q * 8;
        AU ab[16];
        if constexpr (CHAIN) {
#pragma unroll
            for (int p = 0; p < 16; p++)
                ab[p].v = *(const f16x8*)(arow + (wave * 16 + p) * 32);
            // sentinel validation (ack-free producer): rare slow path only
            bool bad = false;
#pragma unroll
            for (int p = 0; p < 16; p++)
                bad = bad | (ab[p].u[0] == SENT_ULL) | (ab[p].u[1] == SENT_ULL);
            if (t > 0 && __ballot(bad) != 0ull) {
                const unsigned long long* abase = (const unsigned long long*)arow;
                for (;;) {
#pragma unroll
                    for (int p = 0; p < 16; p++) {
                        const unsigned long long* a = abase + (size_t)(wave * 16 + p) * 8;
                        ab[p].u[0] = __hip_atomic_load(a,     __ATOMIC_RELAXED, __HIP_MEMORY_SCOPE_AGENT);
                        ab[p].u[1] = __hip_atomic_load(a + 1, __ATOMIC_RELAXED, __HIP_MEMORY_SCOPE_AGENT);
                    }
                    bool b2 = false;
#pragma unroll
                    for (int p = 0; p < 16; p++)
                        b2 = b2 | (ab[p].u[0] == SENT_ULL) | (ab[p].u[1] == SENT_ULL);
                    if (__ballot(b2) == 0ull) break;
                    __builtin_amdgcn_s_sleep(1);
                }
            }
            __asm__ volatile("" ::: "memory");
        } else {
#pragma unroll
            for (int p = 0; p < 16; p++) {
                ab[p].u[0] = __hip_atomic_load((unsigned long long*)(arow + (wave * 16 + p) * 32),
                                               __ATOMIC_RELAXED, __HIP_MEMORY_SCOPE_AGENT);
                ab[p].u[1] = __hip_atomic_load((unsigned long long*)(arow + (wave * 16 + p) * 32) + 1,
                                               __ATOMIC_RELAXED, __HIP_MEMORY_SCOPE_AGENT);
            }
        }

        f32x4 acc[2] = {};
#pragma unroll
        for (int p = 0; p < 16; p++) {
            int kb = wave * 16 + p;
            acc[0] = __builtin_amdgcn_mfma_f32_16x16x32_f16(ab[p].v, wfrag[kb * 128 + lane],      acc[0], 0, 0, 0);
            acc[1] = __builtin_amdgcn_mfma_f32_16x16x32_f16(ab[p].v, wfrag[kb * 128 + 64 + lane], acc[1], 0, 0, 0);
        }

        // partials to LDS (b128, conflict-free), then flag
#pragma unroll
        for (int h = 0; h < 2; h++)
            *(f32x4*)&part[wave][h][lane * 4] = acc[h];
        __asm__ volatile("s_waitcnt lgkmcnt(0)" ::: "memory");
        if (lane == 0)
            __hip_atomic_store(&pdone[wave], tg, __ATOMIC_RELAXED, __HIP_MEMORY_SCOPE_WORKGROUP);

        if (wave >= 2) {
            if (t == T_STEPS - 1) break;
            while (__hip_atomic_load(&go, __ATOMIC_RELAXED, __HIP_MEMORY_SCOPE_WORKGROUP) < tg) { }
            continue;
        }

        // ---- reducer path (wave 0 = col half 0, wave 1 = col half 1) ----
        for (int w = 0; w < 4; w++)
            if (w != wave)
                while (__hip_atomic_load(&pdone[w], __ATOMIC_RELAXED, __HIP_MEMORY_SCOPE_WORKGROUP) < tg) { }
        __asm__ volatile("" ::: "memory");

        bool last = (t == T_STEPS - 1);
        float vv[4];
#pragma unroll
        for (int s = 0; s < 4; s++) {
            int idx = (s * 16 + r) * 4 + q;       // producer layout: ((row>>2)*16+col)*4+(row&3)
            float sum = part[0][wave][idx] + part[1][wave][idx]
                      + part[2][wave][idx] + part[3][wave][idx];
            vv[s] = tanhf(sum * W_INV_SCALE + xp[s]);
            hsl[(q + 4 * s) * 32 + wave * 16 + r] = (_Float16)vv[s];
        }

        // h store FIRST (critical path for all consumers), fire-and-forget:
        // NO ack drain — sentinel validation on the consumer side covers the race.
        if (!last) {
            __asm__ volatile("s_waitcnt lgkmcnt(0)" ::: "memory");
            int rl = lane >> 2, pi = wave * 4 + (lane & 3);
            unsigned long long hv = ((const unsigned long long*)hsl)[rl * 8 + pi];
            __hip_atomic_store((unsigned long long*)(hn + (size_t)(row0 + rl) * H_SZ + n0) + pi,
                               hv, __ATOMIC_RELAXED, __HIP_MEMORY_SCOPE_AGENT);
        }

        // non-critical outputs
#pragma unroll
        for (int s = 0; s < 4; s++) {
            size_t o = (size_t)(row0 + q + 4 * s) * H_SZ + n0 + wave * 16 + r;
            out_t[o] = vv[s];
            if (last) final_out[o] = vv[s];
        }
        if (last) {
            if (wave == 0 && lane == 0)
                __hip_atomic_store(&go, T_STEPS, __ATOMIC_RELAXED, __HIP_MEMORY_SCOPE_WORKGROUP);
            break;
        }

        // prefetch next step's x_proj (h-independent; overlaps barrier)
        const float* out_t1 = out_t + B_SZ * H_SZ;
#pragma unroll
        for (int s = 0; s < 4; s++)
            xp[s] = out_t1[(size_t)(row0 + q + 4 * s) * H_SZ + n0 + wave * 16 + r];

        if (wave == 1) {
            if (lane == 0)
                __hip_atomic_store(&hdone1, tg, __ATOMIC_RELAXED, __HIP_MEMORY_SCOPE_WORKGROUP);
            while (__hip_atomic_load(&go, __ATOMIC_RELAXED, __HIP_MEMORY_SCOPE_WORKGROUP) < tg) { }
            continue;
        }
        // wave 0: group barrier (flat: add + poll both parity lines),
        // arrive as soon as both halves' stores are ISSUED (hdone1).
        while (__hip_atomic_load(&hdone1, __ATOMIC_RELAXED, __HIP_MEMORY_SCOPE_WORKGROUP) < tg) { }
        if (lane == 0)
            __hip_atomic_fetch_add(aline, 1u, __ATOMIC_RELAXED, __HIP_MEMORY_SCOPE_AGENT);
        unsigned int line_tgt = (unsigned int)tg * 32u;
        for (;;) {
            unsigned int v = __hip_atomic_load(ctr + (g * 2 + (lane & 1)) * 32,
                                               __ATOMIC_RELAXED, __HIP_MEMORY_SCOPE_AGENT);
            if (__ballot(v < line_tgt) == 0ull) break;
        }
        if (lane == 0)
            __hip_atomic_store(&go, tg, __ATOMIC_RELAXED, __HIP_MEMORY_SCOPE_WORKGROUP);
    }
}

// ---------------- launcher ----------------

extern "C" void kernel_launch(void* const* d_in, const int* in_sizes, int n_in,
                              void* d_out, int out_size, void* d_ws, size_t ws_size,
                              hipStream_t stream) {
    const float* inputs = (const float*)d_in[0];   // [T,B,D]
    const float* state  = (const float*)d_in[1];   // [B,H]
    const float* W_xh   = (const float*)d_in[2];   // [D,H]
    const float* W_hh   = (const float*)d_in[3];   // [H,H]
    const float* b_h    = (const float*)d_in[4];   // [H]
    float* out = (float*)d_out;
    char* ws = (char*)d_ws;

    const size_t MB = 1ull << 20;
    const size_t XIN_BYTES = (size_t)T_STEPS * B_SZ * D_SZ * 2;   // 32 MB fp16 inputs

    // chain layout: [WxT 4MB][WhT 8MB][ctr 8KB][xin 32MB][h chain: 257 x 256KB]
    // xin must NOT alias the chain: slots 1..256 are sentinel-prefilled.
    const size_t OFF_WXT   = 0;
    const size_t OFF_WHT   = 4 * MB;
    const size_t OFF_CTR   = 12 * MB;
    const size_t OFF_XIN   = 12 * MB + 8192;
    const size_t OFF_CHAIN = OFF_XIN + XIN_BYTES;
    const size_t NEED_CHAIN = OFF_CHAIN + (size_t)(T_STEPS + 1) * HBUF * 2;

    // fallback (ping-pong) layout
    const size_t F_IN  = 0;
    const size_t F_WXT = F_IN  + XIN_BYTES;
    const size_t F_WHT = F_WXT + (size_t)H_SZ * D_SZ * 2;
    const size_t F_H0  = F_WHT + (size_t)H_SZ * H_SZ * 2;
    const size_t F_H1  = F_H0  + (size_t)HBUF * 2;
    const size_t F_CTR = F_H1  + (size_t)HBUF * 2;
    const size_t NEED_PP = F_CTR + 4096;

    dim3 g1((T_STEPS * B_SZ) / 128, H_SZ / 128);
    float* final_out = out + (size_t)T_STEPS * B_SZ * H_SZ;

    if (ws_size >= NEED_CHAIN) {
        _Float16* WxT    = (_Float16*)(ws + OFF_WXT);
        _Float16* WhT    = (_Float16*)(ws + OFF_WHT);
        unsigned int* ctr = (unsigned int*)(ws + OFF_CTR);
        _Float16* xin    = (_Float16*)(ws + OFF_XIN);
        _Float16* hchain = (_Float16*)(ws + OFF_CHAIN);          // h_0
        _Float16* hb1 = nullptr;

        prep_all<<<PREP_TOT, 256, 0, stream>>>(inputs, xin, W_xh, WxT,
                                               W_hh, WhT, state, hchain, ctr,
                                               (uint4*)(hchain + HBUF));

        gemm_xproj<<<g1, 256, 0, stream>>>(xin, WxT, b_h, out,
                                           T_STEPS * B_SZ, H_SZ, D_SZ);

        void* args[] = { (void*)&hchain, (void*)&hb1, (void*)&WhT,
                         (void*)&out, (void*)&final_out, (void*)&ctr };
        hipLaunchCooperativeKernel((void*)rnn_persist<true>, dim3(NBLK), dim3(TPB),
                                   args, 0, stream);
    } else {
        if (ws_size < NEED_PP) return;
        _Float16* inputs_f16 = (_Float16*)(ws + F_IN);
        _Float16* WxT    = (_Float16*)(ws + F_WXT);
        _Float16* WhT    = (_Float16*)(ws + F_WHT);
        _Float16* hbuf0  = (_Float16*)(ws + F_H0);
        _Float16* hbuf1  = (_Float16*)(ws + F_H1);
        unsigned int* ctr = (unsigned int*)(ws + F_CTR);

        prep_all<<<PREP_TOT, 256, 0, stream>>>(inputs, inputs_f16, W_xh, WxT,
                                               W_hh, WhT, state, hbuf0, ctr,
                                               (uint4*)nullptr);

        gemm_xproj<<<g1, 256, 0, stream>>>(inputs_f16, WxT, b_h, out,
                                           T_STEPS * B_SZ, H_SZ, D_SZ);

        void* args[] = { (void*)&hbuf0, (void*)&hbuf1, (void*)&WhT,
                         (void*)&out, (void*)&final_out, (void*)&ctr };
        hipLaunchCooperativeKernel((void*)rnn_persist<false>, dim3(NBLK), dim3(TPB),
                                   args, 0, stream);
    }
}